// Round 9
// baseline (108.975 us; speedup 1.0000x reference)
//
#include <hip/hip_runtime.h>

// VectorQuantizer: z (32,64,64,64) fp32, codebook (1024,64) fp32.
// out = [z_q_st flat (8388608), vq_loss (1)]  (fp32)
// R9: phase split. vq_quant reads z ONCE, writes A-fragments pre-packed in
// fp8 MFMA layout (8.4 MB) + per-block sum|z|^2 partials (prep folded into
// blocks 0-3). vq_main becomes a lean sweep: 1x b128 A-load, full fp8
// codebook in LDS (paired-unit b128 reads, fully unrolled, max3 argmin,
// 32 waves/CU), R8 epilogue unchanged. fin sums zsq + score partials.

constexpr int DIM    = 64;
constexpr int NCODES = 1024;
constexpr int HWSZ   = 4096;     // 64*64
constexpr int NPOS   = 131072;   // 32*4096
constexpr int BLOCK  = 1024;     // 16 waves
constexpr int PPB    = 256;      // 16 waves * 16 rows
constexpr int GRID   = NPOS / PPB;   // 512 = 2 blocks/CU

typedef float    f32x4  __attribute__((ext_vector_type(4)));
typedef float    f32x2  __attribute__((ext_vector_type(2)));
typedef unsigned uint2v __attribute__((ext_vector_type(2)));
typedef unsigned uint4v __attribute__((ext_vector_type(4)));

// ---- k1: z -> fp8 A-fragments in MFMA layout + sum|z|^2 partials.
// Blocks 0..3 also convert the codebook (fp8 paired-unit layout + cinitT).
__global__ __launch_bounds__(BLOCK, 8) void vq_quant(const float* __restrict__ z,
                                                     const float* __restrict__ cb,
                                                     float* __restrict__ cinitT,
                                                     unsigned* __restrict__ cbq,
                                                     unsigned* __restrict__ zq,
                                                     float* __restrict__ zs) {
    __shared__ float ls_lds[BLOCK / 64];
    const int tid  = threadIdx.x;
    const int w    = tid >> 6;
    const int lane = tid & 63;
    const int q    = lane >> 4;
    const int r    = lane & 15;
    const int p0   = blockIdx.x * PPB;
    const int b    = p0 >> 12;
    const int hwb  = p0 & 4095;

    // lane (w, q, r): position p = p0 + w*16 + r, channels q*8..+7 and 32+q*8..+7
    const float* zb = z + (size_t)b * DIM * HWSZ + hwb + w * 16 + r;
    float sq = 0.f;
    unsigned wd[4];
#pragma unroll
    for (int h = 0; h < 2; h++) {
        float v[8];
#pragma unroll
        for (int i = 0; i < 8; i++) {
            v[i] = zb[(size_t)(h * 32 + q * 8 + i) * HWSZ];
            sq = fmaf(v[i], v[i], sq);
        }
        int lo = 0, hi = 0;
        lo = __builtin_amdgcn_cvt_pk_fp8_f32(v[0], v[1], lo, 0);
        lo = __builtin_amdgcn_cvt_pk_fp8_f32(v[2], v[3], lo, 1);
        hi = __builtin_amdgcn_cvt_pk_fp8_f32(v[4], v[5], hi, 0);
        hi = __builtin_amdgcn_cvt_pk_fp8_f32(v[6], v[7], hi, 1);
        wd[h * 2] = (unsigned)lo; wd[h * 2 + 1] = (unsigned)hi;
    }
    uint4v av = {wd[0], wd[1], wd[2], wd[3]};
    // A-fragment store: tile T = blk*16 + w, 16 B per lane, coalesced b128.
    *(uint4v*)(zq + ((size_t)(blockIdx.x * 16 + w) * 64 + lane) * 4) = av;

    // block-sum of |z|^2 (each element counted once)
#pragma unroll
    for (int off = 32; off > 0; off >>= 1) sq += __shfl_down(sq, off, 64);
    if (lane == 0) ls_lds[w] = sq;
    __syncthreads();
    if (tid == 0) {
        float s = 0.f;
#pragma unroll
        for (int i = 0; i < BLOCK / 64; i++) s += ls_lds[i];
        zs[blockIdx.x] = s;
    }

    // ---- folded prep: blocks 0..3, threads 0..255 -> codebook row j ----
    if (blockIdx.x < 4 && tid < 256) {
        int j = blockIdx.x * 256 + tid;
        const float4* src = (const float4*)(cb + (size_t)j * DIM);
        unsigned words[16];
        float nq = 0.f;
#pragma unroll
        for (int g8 = 0; g8 < 8; g8++) {
            float4 v0 = src[g8 * 2], v1 = src[g8 * 2 + 1];
            int lo = 0, hi = 0;
            lo = __builtin_amdgcn_cvt_pk_fp8_f32(v0.x * 512.f, v0.y * 512.f, lo, 0);
            lo = __builtin_amdgcn_cvt_pk_fp8_f32(v0.z * 512.f, v0.w * 512.f, lo, 1);
            hi = __builtin_amdgcn_cvt_pk_fp8_f32(v1.x * 512.f, v1.y * 512.f, hi, 0);
            hi = __builtin_amdgcn_cvt_pk_fp8_f32(v1.z * 512.f, v1.w * 512.f, hi, 1);
            words[g8 * 2] = (unsigned)lo; words[g8 * 2 + 1] = (unsigned)hi;
#pragma unroll
            for (int m = 0; m < 2; m++) {
                int wv = m ? hi : lo;
                f32x2 d0 = __builtin_amdgcn_cvt_pk_f32_fp8(wv, 0);
                f32x2 d1 = __builtin_amdgcn_cvt_pk_f32_fp8(wv, 1);
                nq += d0[0] * d0[0] + d0[1] * d0[1] + d1[0] * d1[0] + d1[1] * d1[1];
            }
        }
#pragma unroll
        for (int u = 0; u < 4; u++) {
            int us = u ^ (j & 3);
            uint4v t = {words[2 * u], words[2 * u + 1],
                        words[2 * u + 8], words[2 * u + 9]};
            *(uint4v*)(cbq + (size_t)j * 16 + us * 4) = t;
        }
        cinitT[(j & 15) * 64 + (j >> 4)] = 8.f - nq * (1.f / 1024.f);
    }
}

// ---- k2: the sweep. A from zq (1 b128), codebook from LDS, R8 inner loop. ----
__global__ __launch_bounds__(BLOCK, 8) void vq_main(const unsigned* __restrict__ zq,
                                                    const float* __restrict__ cinitT,
                                                    const unsigned* __restrict__ cbq,
                                                    float* __restrict__ out,
                                                    float* __restrict__ sc) {
    __shared__ __align__(16) unsigned char cb_lds[NCODES * DIM];   // 64 KB fp8
    __shared__ int   bj_lds[PPB];                                  // 1 KB
    __shared__ float ls_lds[BLOCK / 64];

    const int tid  = threadIdx.x;
    const int w    = tid >> 6;        // wave 0..15
    const int lane = tid & 63;
    const int q    = lane >> 4;       // quad 0..3
    const int r    = lane & 15;
    const int p0   = blockIdx.x * PPB;
    const int b    = p0 >> 12;
    const int hwb  = p0 & 4095;

    // ---- Stage full fp8 codebook: 64 KB, 4 linear DMA sweeps ----
#pragma unroll
    for (int it = 0; it < (NCODES * DIM) / (BLOCK * 16); it++) {
        int off = (it * BLOCK + tid) * 16;
        __builtin_amdgcn_global_load_lds(
            (const __attribute__((address_space(1))) void*)((const char*)cbq + off),
            (__attribute__((address_space(3))) void*)(cb_lds + off), 16, 0, 0);
    }

    // ---- A fragment: one coalesced b128 from zq (pre-packed MFMA layout) ----
    uint4v av = *(const uint4v*)(zq + ((size_t)(blockIdx.x * 16 + w) * 64 + lane) * 4);
    uint2v a0 = {av[0], av[1]}, a1 = {av[2], av[3]};
    const long afrag0 = __builtin_bit_cast(long, a0);
    const long afrag1 = __builtin_bit_cast(long, a1);

    __syncthreads();   // staging complete; barrier-free until the loss reduce

    // B base: loop-invariant (row&3 == r&3); per-jt offset is jt*1024 (imm).
    const int bbase = r * 64 + ((q ^ (r & 3)) * 16);

    float best[4];     // packed positive scores; float max == uint max here
#pragma unroll
    for (int g = 0; g < 4; g++) best[g] = 0.f;
    float tmp[4];

    // ---- Fully-unrolled sweep: ping-pong B (1x b128 per jt), depth-2 ----
    uint4v Bp[2];
    Bp[0] = *(const uint4v*)&cb_lds[0 * 1024 + bbase];
    Bp[1] = *(const uint4v*)&cb_lds[1 * 1024 + bbase];
    float4 ci[2];
    ci[0] = *(const float4*)(cinitT + r * 64 + 0);
    ci[1] = *(const float4*)(cinitT + r * 64 + 4);

#pragma unroll
    for (int G = 0; G < 16; G++) {
#pragma unroll
        for (int e = 0; e < 4; e++) {
            const int jt   = G * 4 + e;
            const int slot = jt & 1;
            const int row  = jt * 16;            // + r at runtime
            const float cin = ci[G & 1][e];
            const unsigned inv_j = (unsigned)(1023 - row);  // - r folded below
            uint2v blo = {Bp[slot][0], Bp[slot][1]};
            uint2v bhi = {Bp[slot][2], Bp[slot][3]};
            f32x4 c0 = {cin, cin, cin, cin};
            f32x4 acc = __builtin_amdgcn_mfma_f32_16x16x32_fp8_fp8(
                afrag0, __builtin_bit_cast(long, blo), c0, 0, 0, 0);
            acc = __builtin_amdgcn_mfma_f32_16x16x32_fp8_fp8(
                afrag1, __builtin_bit_cast(long, bhi), acc, 0, 0, 0);
#pragma unroll
            for (int g = 0; g < 4; g++) {
                // D = 8 + z.B - |B|^2/1024 > 0 -> monotone bits; low 10 = 1023-j
                unsigned bits = (__float_as_uint(acc[g]) & ~1023u)
                              | (inv_j - (unsigned)r);
                float pf = __uint_as_float(bits);
                if ((jt & 1) == 0) {
                    tmp[g] = pf;                       // stage even jt
                } else {
                    best[g] = fmaxf(fmaxf(best[g], tmp[g]), pf);  // v_max3
                }
            }
            // refill this slot for jt+2 (compile-time immediate offset)
            Bp[slot] = *(const uint4v*)&cb_lds[(((jt + 2) & 63) * 1024) + bbase];
        }
        ci[G & 1] = *(const float4*)(cinitT + r * 64 + (((G + 2) & 15) * 4));
    }

    // ---- Column-argmax reduce over the 16 j-lanes of each quad ----
    unsigned bestu[4];
#pragma unroll
    for (int g = 0; g < 4; g++) {
        unsigned v = __float_as_uint(best[g]);
#pragma unroll
        for (int off = 1; off < 16; off <<= 1) {
            unsigned v2 = __shfl_xor((int)v, off, 64);
            v = v > v2 ? v : v2;
        }
        bestu[g] = v;
    }

    // Writer lane for row m=r: quad q == r>>2 holds best for g == r&3.
    float lsum = 0.f;
    if (q == (r >> 2)) {
        int g = r & 3;
        unsigned v = bestu[0];
        v = (g == 1) ? bestu[1] : v;
        v = (g == 2) ? bestu[2] : v;
        v = (g == 3) ? bestu[3] : v;
        bj_lds[w * 16 + r] = 1023 - (int)(v & 1023u);
        // dist - |z|^2 = (8 - D)/256  (|z|^2 added back in fin via zs partials)
        lsum = (8.f - __uint_as_float(v)) * (1.f / 256.f);
    }
#pragma unroll
    for (int off = 32; off > 0; off >>= 1) lsum += __shfl_down(lsum, off, 64);
    if (lane == 0) ls_lds[w] = lsum;
    __syncthreads();
    if (tid == 0) {
        float s = 0.f;
#pragma unroll
        for (int i = 0; i < BLOCK / 64; i++) s += ls_lds[i];
        sc[blockIdx.x] = s;              // plain store; no fence, no atomics
    }

    // ---- Epilogue: dequantize fp8 row from LDS (paired-unit layout),
    // scatter NCHW; 64 consecutive positions per store instr. ----
    int posi = tid & 255;
    int u    = tid >> 8;                 // unit 0..3 -> channels {8u..}, {32+8u..}
    int myj  = bj_lds[posi];
    int us   = u ^ (myj & 3);
    uint4v t = *(const uint4v*)&cb_lds[(size_t)myj * 64 + us * 16];
    float* ob = out + (size_t)b * DIM * HWSZ + hwb + posi;
#pragma unroll
    for (int m = 0; m < 2; m++) {        // m=0: group u, m=1: group u+4
        int cbase = (m == 0) ? (8 * u) : (32 + 8 * u);
#pragma unroll
        for (int wdx = 0; wdx < 2; wdx++) {
            int word = (int)t[m * 2 + wdx];
            f32x2 d0 = __builtin_amdgcn_cvt_pk_f32_fp8(word, 0);
            f32x2 d1 = __builtin_amdgcn_cvt_pk_f32_fp8(word, 1);
            ob[(size_t)(cbase + wdx * 4 + 0) * HWSZ] = d0[0] * (1.f / 512.f);
            ob[(size_t)(cbase + wdx * 4 + 1) * HWSZ] = d0[1] * (1.f / 512.f);
            ob[(size_t)(cbase + wdx * 4 + 2) * HWSZ] = d1[0] * (1.f / 512.f);
            ob[(size_t)(cbase + wdx * 4 + 3) * HWSZ] = d1[1] * (1.f / 512.f);
        }
    }
}

__global__ void vq_fin(const float* __restrict__ zs, const float* __restrict__ sc,
                       float* __restrict__ out_loss) {
    int t = threadIdx.x;   // 64 threads, 1 wave
    float s = 0.f;
#pragma unroll
    for (int k = 0; k < GRID / 64; k++) s += zs[t + k * 64] + sc[t + k * 64];
#pragma unroll
    for (int off = 32; off > 0; off >>= 1) s += __shfl_down(s, off, 64);
    if (t == 0) out_loss[0] = 1.25f * s / (float)((size_t)NPOS * DIM);
}

extern "C" void kernel_launch(void* const* d_in, const int* in_sizes, int n_in,
                              void* d_out, int out_size, void* d_ws, size_t ws_size,
                              hipStream_t stream) {
    const float* z  = (const float*)d_in[0];
    const float* cb = (const float*)d_in[1];
    float* out = (float*)d_out;

    float*    cinitT = (float*)d_ws;                                 // 4 KB
    unsigned* cbq    = (unsigned*)((char*)d_ws + 4096);              // 64 KB
    unsigned* zq     = (unsigned*)((char*)d_ws + 4096 + 65536);      // 8 MB
    float*    zs     = (float*)((char*)d_ws + 4096 + 65536 + 8388608);        // 2 KB
    float*    sc     = (float*)((char*)d_ws + 4096 + 65536 + 8388608 + 2048); // 2 KB

    vq_quant<<<GRID, BLOCK, 0, stream>>>(z, cb, cinitT, cbq, zq, zs);
    vq_main<<<GRID, BLOCK, 0, stream>>>(zq, cinitT, cbq, out, sc);
    vq_fin<<<1, 64, 0, stream>>>(zs, sc, out + (size_t)NPOS * DIM);
}